// Round 6
// baseline (454.791 us; speedup 1.0000x reference)
//
#include <hip/hip_runtime.h>
#include <math.h>

// ---------------------------------------------------------------------------
// TopoGAT: 2-layer GAT on MI355X.
// R2: agg kernels unrolled x8 (8 outstanding row gathers/wave).
// R3: CSR build via two-level binning (write-locality; ~1x writeback).
// R4: xform kernels: thread = node, acc[] in VGPRs, W via s_load (L2-hot).
// R5: gather tables h1/g stored in bf16 (halves fabric bytes of the
//     random-row gathers, the measured 3.1 TB/s limiter). Attention dots
//     still computed from fp32 accumulators -> weights unaffected.
// ---------------------------------------------------------------------------

#define NBUK_MAX 512
#define BIN_CHUNK 4096

typedef unsigned short ushort_t;

__device__ inline unsigned int f2bf(float f) {  // RNE fp32->bf16
    unsigned int u = __float_as_uint(f);
    u += 0x7FFFu + ((u >> 16) & 1u);
    return u >> 16;
}
__device__ inline float bf2f(ushort_t b) {
    return __uint_as_float((unsigned int)b << 16);
}

__device__ inline int wave_incl_scan(int v, int lane) {
    #pragma unroll
    for (int ofs = 1; ofs < 64; ofs <<= 1) {
        int t = __shfl_up(v, ofs);
        if (lane >= ofs) v += t;
    }
    return v;
}

// Bucket histogram (bucket = dst>>8), LDS-aggregated.
__global__ __launch_bounds__(256) void k_bhist(const int* __restrict__ dst,
                                               int* __restrict__ bucketCnt,
                                               int E, int NBUK) {
    __shared__ int h[NBUK_MAX];
    int tid = threadIdx.x;
    for (int i = tid; i < NBUK; i += 256) h[i] = 0;
    __syncthreads();
    for (int i = blockIdx.x * 256 + tid; i < E; i += gridDim.x * 256)
        atomicAdd(&h[dst[i] >> 8], 1);
    __syncthreads();
    for (int i = tid; i < NBUK; i += 256) {
        int c = h[i];
        if (c) atomicAdd(&bucketCnt[i], c);
    }
}

// One-wave exclusive scan of bucket counts -> bucketOff, gCursor.
__global__ void k_bscan(const int* __restrict__ bucketCnt,
                        int* __restrict__ bucketOff, int* __restrict__ gCursor,
                        int* __restrict__ rowptr, int N, int E, int NBUK) {
    int lane = threadIdx.x & 63;
    int running = 0;
    for (int base = 0; base < NBUK; base += 64) {
        int idx = base + lane;
        int v = (idx < NBUK) ? bucketCnt[idx] : 0;
        int incl = wave_incl_scan(v, lane);
        int excl = running + incl - v;
        if (idx < NBUK) { bucketOff[idx] = excl; gCursor[idx] = excl; }
        running += __shfl(incl, 63);
    }
    if (lane == 0) { bucketOff[NBUK] = running; rowptr[N] = E; }
}

// Bin edges into bucket-contiguous tmp. One global atomic per (block,bucket);
// packed word = (src<<8) | (dst&255).
__global__ __launch_bounds__(256) void k_bin(const int* __restrict__ src,
                                             const int* __restrict__ dst,
                                             int* __restrict__ gCursor,
                                             unsigned int* __restrict__ tmp,
                                             int E, int NBUK) {
    __shared__ int lcnt[NBUK_MAX];
    __shared__ int lcur[NBUK_MAX];
    int tid = threadIdx.x;
    int base = blockIdx.x * BIN_CHUNK;
    for (int i = tid; i < NBUK; i += 256) lcnt[i] = 0;
    __syncthreads();
    #pragma unroll
    for (int k = 0; k < BIN_CHUNK / 256; k++) {
        int i = base + tid + k * 256;
        if (i < E) atomicAdd(&lcnt[dst[i] >> 8], 1);
    }
    __syncthreads();
    for (int b = tid; b < NBUK; b += 256) {
        int c = lcnt[b];
        lcur[b] = c ? atomicAdd(&gCursor[b], c) : 0;
    }
    __syncthreads();
    #pragma unroll
    for (int k = 0; k < BIN_CHUNK / 256; k++) {
        int i = base + tid + k * 256;
        if (i < E) {
            int d = dst[i];
            int p = atomicAdd(&lcur[d >> 8], 1);
            tmp[p] = ((unsigned int)src[i] << 8) | (unsigned int)(d & 255);
        }
    }
}

// Exact CSR fill within a bucket; csr writes confined to block-owned window.
__global__ __launch_bounds__(256) void k_fill2(const unsigned int* __restrict__ tmp,
                                               const int* __restrict__ bucketOff,
                                               int* __restrict__ rowptr,
                                               int* __restrict__ csr, int N) {
    __shared__ int cnt[256];
    __shared__ int cur[256];
    __shared__ int wsum[4];
    int b = blockIdx.x, tid = threadIdx.x;
    int lane = tid & 63, wv = tid >> 6;
    int e0 = bucketOff[b], e1 = bucketOff[b + 1];
    cnt[tid] = 0;
    __syncthreads();
    for (int i = e0 + tid; i < e1; i += 256)
        atomicAdd(&cnt[tmp[i] & 255u], 1);
    __syncthreads();
    int v = cnt[tid];
    int incl = wave_incl_scan(v, lane);
    if (lane == 63) wsum[wv] = incl;
    __syncthreads();
    int woff = 0;
    for (int i = 0; i < wv; i++) woff += wsum[i];
    int excl = woff + incl - v;
    int node = b * 256 + tid;
    if (node < N) rowptr[node] = e0 + excl;
    cur[tid] = e0 + excl;
    __syncthreads();
    for (int i = e0 + tid; i < e1; i += 256) {
        unsigned int t = tmp[i];
        int p = atomicAdd(&cur[t & 255u], 1);
        csr[p] = (int)(t >> 8);
    }
}

// h1b[n][64](bf16) = [x[n]|topo[n]] @ W1 ; as1/ad1 from fp32 accumulators.
// Thread = node; W accesses thread-uniform -> s_load.
__global__ __launch_bounds__(256, 4) void k_xform1(const float* __restrict__ x,
                                                   const float* __restrict__ topo,
                                                   const float* __restrict__ W1,
                                                   const float* __restrict__ asrc,
                                                   const float* __restrict__ adst,
                                                   ushort_t* __restrict__ h1b,
                                                   float* __restrict__ as1,
                                                   float* __restrict__ ad1, int N) {
    int n = blockIdx.x * 256 + threadIdx.x;
    if (n >= N) n = N - 1;  // tail: duplicate compute, identical writes (benign)
    const float4* xr = (const float4*)(x + (size_t)n * 128);
    float acc[64];
    #pragma unroll
    for (int c = 0; c < 64; c++) acc[c] = 0.f;
    float4 xv = xr[0];
    #pragma unroll 1
    for (int k4 = 0; k4 < 32; k4++) {
        float4 cur = xv;
        if (k4 < 31) xv = xr[k4 + 1];  // prefetch next chunk
        const float* Wk = W1 + k4 * 256;  // rows 4k..4k+3 of W1[136][64]
        #pragma unroll
        for (int c = 0; c < 64; c++) acc[c] = fmaf(cur.x, Wk[c], acc[c]);
        #pragma unroll
        for (int c = 0; c < 64; c++) acc[c] = fmaf(cur.y, Wk[64 + c], acc[c]);
        #pragma unroll
        for (int c = 0; c < 64; c++) acc[c] = fmaf(cur.z, Wk[128 + c], acc[c]);
        #pragma unroll
        for (int c = 0; c < 64; c++) acc[c] = fmaf(cur.w, Wk[192 + c], acc[c]);
    }
    const float4* tr = (const float4*)(topo + (size_t)n * 8);
    float4 t0 = tr[0], t1 = tr[1];
    float tv[8] = {t0.x, t0.y, t0.z, t0.w, t1.x, t1.y, t1.z, t1.w};
    #pragma unroll
    for (int j = 0; j < 8; j++) {
        const float* Wk = W1 + (128 + j) * 64;
        #pragma unroll
        for (int c = 0; c < 64; c++) acc[c] = fmaf(tv[j], Wk[c], acc[c]);
    }
    // bf16 row store: 64 x 2B = 128B via 8 uint4
    unsigned int pk[32];
    #pragma unroll
    for (int q = 0; q < 32; q++)
        pk[q] = f2bf(acc[2 * q]) | (f2bf(acc[2 * q + 1]) << 16);
    uint4* ho = (uint4*)(h1b + (size_t)n * 64);
    #pragma unroll
    for (int q = 0; q < 8; q++)
        ho[q] = make_uint4(pk[4 * q], pk[4 * q + 1], pk[4 * q + 2], pk[4 * q + 3]);
    float svv[8], dvv[8];
    #pragma unroll
    for (int h = 0; h < 8; h++) {
        float s = 0.f, d = 0.f;
        #pragma unroll
        for (int ch = 0; ch < 8; ch++) {
            s = fmaf(acc[h * 8 + ch], asrc[h * 8 + ch], s);
            d = fmaf(acc[h * 8 + ch], adst[h * 8 + ch], d);
        }
        svv[h] = s; dvv[h] = d;
    }
    float4* aso = (float4*)(as1 + (size_t)n * 8);
    aso[0] = make_float4(svv[0], svv[1], svv[2], svv[3]);
    aso[1] = make_float4(svv[4], svv[5], svv[6], svv[7]);
    float4* ado = (float4*)(ad1 + (size_t)n * 8);
    ado[0] = make_float4(dvv[0], dvv[1], dvv[2], dvv[3]);
    ado[1] = make_float4(dvv[4], dvv[5], dvv[6], dvv[7]);
}

// Per-dst softmax-weighted aggregation over in-edges (+ implicit self loop).
// Edge loop unrolled x8; h1 rows are bf16 (128B/row gather).
__global__ __launch_bounds__(256) void k_agg1(const ushort_t* __restrict__ h1b,
                                              const float* __restrict__ as1,
                                              const float* __restrict__ ad1,
                                              const float* __restrict__ b1,
                                              const int* __restrict__ rowptr,
                                              const int* __restrict__ csr,
                                              float* __restrict__ h2, int N) {
    int tid = threadIdx.x, lane = tid & 63;
    int n = blockIdx.x * 4 + (tid >> 6);
    if (n >= N) return;
    int myh = lane >> 3;
    float ad_d = ad1[n * 8 + myh];
    float e0 = as1[n * 8 + myh] + ad_d;  // self loop
    float w0s = __expf(e0 >= 0.f ? e0 : 0.2f * e0);
    float acc0 = w0s * bf2f(h1b[(size_t)n * 64 + lane]), z0 = w0s;
    float acc1 = 0.f, z1 = 0.f, acc2 = 0.f, z2 = 0.f, acc3 = 0.f, z3 = 0.f;
    int j0 = rowptr[n], j1 = rowptr[n + 1];
    int j = j0;
    for (; j + 8 <= j1; j += 8) {
        int s0 = csr[j + 0], s1 = csr[j + 1], s2 = csr[j + 2], s3 = csr[j + 3];
        int s4 = csr[j + 4], s5 = csr[j + 5], s6 = csr[j + 6], s7 = csr[j + 7];
        ushort_t u0 = h1b[(size_t)s0 * 64 + lane];
        ushort_t u1 = h1b[(size_t)s1 * 64 + lane];
        ushort_t u2 = h1b[(size_t)s2 * 64 + lane];
        ushort_t u3 = h1b[(size_t)s3 * 64 + lane];
        ushort_t u4 = h1b[(size_t)s4 * 64 + lane];
        ushort_t u5 = h1b[(size_t)s5 * 64 + lane];
        ushort_t u6 = h1b[(size_t)s6 * 64 + lane];
        ushort_t u7 = h1b[(size_t)s7 * 64 + lane];
        float a0 = as1[s0 * 8 + myh], a1 = as1[s1 * 8 + myh];
        float a2 = as1[s2 * 8 + myh], a3 = as1[s3 * 8 + myh];
        float a4 = as1[s4 * 8 + myh], a5 = as1[s5 * 8 + myh];
        float a6 = as1[s6 * 8 + myh], a7 = as1[s7 * 8 + myh];
        float q0 = a0 + ad_d, q1 = a1 + ad_d, q2 = a2 + ad_d, q3 = a3 + ad_d;
        float q4 = a4 + ad_d, q5 = a5 + ad_d, q6 = a6 + ad_d, q7 = a7 + ad_d;
        float w0 = __expf(q0 >= 0.f ? q0 : 0.2f * q0);
        float w1 = __expf(q1 >= 0.f ? q1 : 0.2f * q1);
        float w2 = __expf(q2 >= 0.f ? q2 : 0.2f * q2);
        float w3 = __expf(q3 >= 0.f ? q3 : 0.2f * q3);
        float w4 = __expf(q4 >= 0.f ? q4 : 0.2f * q4);
        float w5 = __expf(q5 >= 0.f ? q5 : 0.2f * q5);
        float w6 = __expf(q6 >= 0.f ? q6 : 0.2f * q6);
        float w7 = __expf(q7 >= 0.f ? q7 : 0.2f * q7);
        acc0 = fmaf(w0, bf2f(u0), acc0); z0 += w0;
        acc1 = fmaf(w1, bf2f(u1), acc1); z1 += w1;
        acc2 = fmaf(w2, bf2f(u2), acc2); z2 += w2;
        acc3 = fmaf(w3, bf2f(u3), acc3); z3 += w3;
        acc0 = fmaf(w4, bf2f(u4), acc0); z0 += w4;
        acc1 = fmaf(w5, bf2f(u5), acc1); z1 += w5;
        acc2 = fmaf(w6, bf2f(u6), acc2); z2 += w6;
        acc3 = fmaf(w7, bf2f(u7), acc3); z3 += w7;
    }
    for (; j < j1; ++j) {
        int s = csr[j];
        float e = as1[s * 8 + myh] + ad_d;
        float ww = __expf(e >= 0.f ? e : 0.2f * e);
        acc0 = fmaf(ww, bf2f(h1b[(size_t)s * 64 + lane]), acc0);
        z0 += ww;
    }
    float acc = (acc0 + acc1) + (acc2 + acc3);
    float z = (z0 + z1) + (z2 + z3);
    float v = acc / (z + 1e-16f) + b1[lane];
    h2[(size_t)n * 64 + lane] = v > 0.f ? v : (__expf(v) - 1.f);  // ELU
}

// gb[n][40](bf16) = h2[n] @ W2 ; as2/ad2 from fp32 accumulators.
__global__ __launch_bounds__(256, 4) void k_xform2(const float* __restrict__ h2,
                                                   const float* __restrict__ W2,
                                                   const float* __restrict__ asrc2,
                                                   const float* __restrict__ adst2,
                                                   ushort_t* __restrict__ gb,
                                                   float* __restrict__ as2,
                                                   float* __restrict__ ad2, int N) {
    int n = blockIdx.x * 256 + threadIdx.x;
    if (n >= N) n = N - 1;
    const float4* hr = (const float4*)(h2 + (size_t)n * 64);
    float acc[40];
    #pragma unroll
    for (int c = 0; c < 40; c++) acc[c] = 0.f;
    float4 xv = hr[0];
    #pragma unroll 1
    for (int k4 = 0; k4 < 16; k4++) {
        float4 cur = xv;
        if (k4 < 15) xv = hr[k4 + 1];
        const float* Wk = W2 + k4 * 160;  // rows 4k..4k+3 of W2[64][40]
        #pragma unroll
        for (int c = 0; c < 40; c++) acc[c] = fmaf(cur.x, Wk[c], acc[c]);
        #pragma unroll
        for (int c = 0; c < 40; c++) acc[c] = fmaf(cur.y, Wk[40 + c], acc[c]);
        #pragma unroll
        for (int c = 0; c < 40; c++) acc[c] = fmaf(cur.z, Wk[80 + c], acc[c]);
        #pragma unroll
        for (int c = 0; c < 40; c++) acc[c] = fmaf(cur.w, Wk[120 + c], acc[c]);
    }
    float s = 0.f, d = 0.f;
    #pragma unroll
    for (int c = 0; c < 40; c++) {
        s = fmaf(acc[c], asrc2[c], s);
        d = fmaf(acc[c], adst2[c], d);
    }
    as2[n] = s;
    ad2[n] = d;
    // bf16 row store: 40 x 2B = 80B via 5 uint4
    unsigned int pk[20];
    #pragma unroll
    for (int q = 0; q < 20; q++)
        pk[q] = f2bf(acc[2 * q]) | (f2bf(acc[2 * q + 1]) << 16);
    uint4* go = (uint4*)(gb + (size_t)n * 40);
    #pragma unroll
    for (int q = 0; q < 5; q++)
        go[q] = make_uint4(pk[4 * q], pk[4 * q + 1], pk[4 * q + 2], pk[4 * q + 3]);
}

// Layer-2 aggregation + bias + log_softmax. Edge loop unrolled x8; g bf16.
__global__ __launch_bounds__(256) void k_agg2(const ushort_t* __restrict__ gb,
                                              const float* __restrict__ as2,
                                              const float* __restrict__ ad2,
                                              const float* __restrict__ b2,
                                              const int* __restrict__ rowptr,
                                              const int* __restrict__ csr,
                                              float* __restrict__ out, int N) {
    int tid = threadIdx.x, lane = tid & 63;
    int n = blockIdx.x * 4 + (tid >> 6);
    if (n >= N) return;
    int c = (lane < 40) ? lane : 0;
    float add = ad2[n];
    float e0 = as2[n] + add;
    float w0s = __expf(e0 >= 0.f ? e0 : 0.2f * e0);
    float acc0 = w0s * bf2f(gb[(size_t)n * 40 + c]), z0 = w0s;
    float acc1 = 0.f, z1 = 0.f, acc2 = 0.f, z2 = 0.f, acc3 = 0.f, z3 = 0.f;
    int j0 = rowptr[n], j1 = rowptr[n + 1];
    int j = j0;
    for (; j + 8 <= j1; j += 8) {
        int s0 = csr[j + 0], s1 = csr[j + 1], s2 = csr[j + 2], s3 = csr[j + 3];
        int s4 = csr[j + 4], s5 = csr[j + 5], s6 = csr[j + 6], s7 = csr[j + 7];
        ushort_t u0 = gb[(size_t)s0 * 40 + c];
        ushort_t u1 = gb[(size_t)s1 * 40 + c];
        ushort_t u2 = gb[(size_t)s2 * 40 + c];
        ushort_t u3 = gb[(size_t)s3 * 40 + c];
        ushort_t u4 = gb[(size_t)s4 * 40 + c];
        ushort_t u5 = gb[(size_t)s5 * 40 + c];
        ushort_t u6 = gb[(size_t)s6 * 40 + c];
        ushort_t u7 = gb[(size_t)s7 * 40 + c];
        float a0 = as2[s0], a1 = as2[s1], a2 = as2[s2], a3 = as2[s3];
        float a4 = as2[s4], a5 = as2[s5], a6 = as2[s6], a7 = as2[s7];
        float q0 = a0 + add, q1 = a1 + add, q2 = a2 + add, q3 = a3 + add;
        float q4 = a4 + add, q5 = a5 + add, q6 = a6 + add, q7 = a7 + add;
        float w0 = __expf(q0 >= 0.f ? q0 : 0.2f * q0);
        float w1 = __expf(q1 >= 0.f ? q1 : 0.2f * q1);
        float w2 = __expf(q2 >= 0.f ? q2 : 0.2f * q2);
        float w3 = __expf(q3 >= 0.f ? q3 : 0.2f * q3);
        float w4 = __expf(q4 >= 0.f ? q4 : 0.2f * q4);
        float w5 = __expf(q5 >= 0.f ? q5 : 0.2f * q5);
        float w6 = __expf(q6 >= 0.f ? q6 : 0.2f * q6);
        float w7 = __expf(q7 >= 0.f ? q7 : 0.2f * q7);
        acc0 = fmaf(w0, bf2f(u0), acc0); z0 += w0;
        acc1 = fmaf(w1, bf2f(u1), acc1); z1 += w1;
        acc2 = fmaf(w2, bf2f(u2), acc2); z2 += w2;
        acc3 = fmaf(w3, bf2f(u3), acc3); z3 += w3;
        acc0 = fmaf(w4, bf2f(u4), acc0); z0 += w4;
        acc1 = fmaf(w5, bf2f(u5), acc1); z1 += w5;
        acc2 = fmaf(w6, bf2f(u6), acc2); z2 += w6;
        acc3 = fmaf(w7, bf2f(u7), acc3); z3 += w7;
    }
    for (; j < j1; ++j) {
        int s = csr[j];
        float e = as2[s] + add;
        float ww = __expf(e >= 0.f ? e : 0.2f * e);
        acc0 = fmaf(ww, bf2f(gb[(size_t)s * 40 + c]), acc0);
        z0 += ww;
    }
    float acc = (acc0 + acc1) + (acc2 + acc3);
    float z = (z0 + z1) + (z2 + z3);
    float logit = acc / (z + 1e-16f) + b2[c];
    float mv = (lane < 40) ? logit : -INFINITY;
    #pragma unroll
    for (int ofs = 1; ofs < 64; ofs <<= 1) mv = fmaxf(mv, __shfl_xor(mv, ofs));
    float ev = (lane < 40) ? __expf(logit - mv) : 0.f;
    #pragma unroll
    for (int ofs = 1; ofs < 64; ofs <<= 1) ev += __shfl_xor(ev, ofs);
    if (lane < 40) out[n * 40 + lane] = logit - mv - __logf(ev);
}

extern "C" void kernel_launch(void* const* d_in, const int* in_sizes, int n_in,
                              void* d_out, int out_size, void* d_ws, size_t ws_size,
                              hipStream_t stream) {
    const float* x    = (const float*)d_in[0];
    const float* topo = (const float*)d_in[1];
    const int*   ei   = (const int*)d_in[2];
    const float* W1   = (const float*)d_in[3];
    const float* a_s1 = (const float*)d_in[4];
    const float* a_d1 = (const float*)d_in[5];
    const float* b1   = (const float*)d_in[6];
    const float* W2   = (const float*)d_in[7];
    const float* a_s2 = (const float*)d_in[8];
    const float* a_d2 = (const float*)d_in[9];
    const float* b2   = (const float*)d_in[10];
    float* out = (float*)d_out;

    int N = in_sizes[0] / 128;
    int E = in_sizes[2] / 2;
    const int* esrc = ei;
    const int* edst = ei + E;
    int NBUK = (N + 255) / 256;

    char* ws = (char*)d_ws;
    size_t off = 0;
    auto alloc = [&](size_t bytes) -> void* {
        void* p = ws + off;
        off = (off + bytes + 255) & ~(size_t)255;
        return p;
    };
    ushort_t* h1b  = (ushort_t*)alloc((size_t)N * 64 * 2);
    float* as1     = (float*)alloc((size_t)N * 8 * 4);
    float* ad1     = (float*)alloc((size_t)N * 8 * 4);
    float* h2      = (float*)alloc((size_t)N * 64 * 4);
    ushort_t* gb   = (ushort_t*)alloc((size_t)N * 40 * 2);
    float* as2     = (float*)alloc((size_t)N * 4);
    float* ad2     = (float*)alloc((size_t)N * 4);
    int*   rowptr  = (int*)alloc((size_t)(N + 1) * 4);
    int*   csr     = (int*)alloc((size_t)E * 4);
    unsigned int* tmp = (unsigned int*)alloc((size_t)E * 4);
    int* bucketCnt = (int*)alloc((size_t)(NBUK + 1) * 4);
    int* bucketOff = (int*)alloc((size_t)(NBUK + 1) * 4);
    int* gCursor   = (int*)alloc((size_t)NBUK * 4);

    hipMemsetAsync(bucketCnt, 0, (size_t)(NBUK + 1) * 4, stream);
    k_bhist<<<256, 256, 0, stream>>>(edst, bucketCnt, E, NBUK);
    k_bscan<<<1, 64, 0, stream>>>(bucketCnt, bucketOff, gCursor, rowptr, N, E, NBUK);
    int nbin = (E + BIN_CHUNK - 1) / BIN_CHUNK;
    k_bin<<<nbin, 256, 0, stream>>>(esrc, edst, gCursor, tmp, E, NBUK);
    k_fill2<<<NBUK, 256, 0, stream>>>(tmp, bucketOff, rowptr, csr, N);

    int nbx = (N + 255) / 256;  // thread = node
    int nb4 = (N + 3) / 4;      // 1 node/wave x 4 waves/block
    k_xform1<<<nbx, 256, 0, stream>>>(x, topo, W1, a_s1, a_d1, h1b, as1, ad1, N);
    k_agg1<<<nb4, 256, 0, stream>>>(h1b, as1, ad1, b1, rowptr, csr, h2, N);
    k_xform2<<<nbx, 256, 0, stream>>>(h2, W2, a_s2, a_d2, gb, as2, ad2, N);
    k_agg2<<<nb4, 256, 0, stream>>>(gb, as2, ad2, b2, rowptr, csr, out, N);
}